// Round 16
// baseline (58.758 us; speedup 1.0000x reference)
//
#include <hip/hip_runtime.h>

// FullAttention_Spatial: N=4, L=S=1024, H=16, E=D=64, NUM_POS=2, fp32 in/out.
//
// score = temp*(QK + attn_mask[l,s] + klm[n,s]) + pos_table[pos[n,l,s]][h]
// pos in {0,1} => bias = T0[h] + bit*(T1[h]-T0[h]); T0 cancels in softmax.
// Log2-domain softmax; Q pre-scaled by temp2 = temp*log2e.
//
// R15 = R14 + 8B-granularity LDS swizzle: panels store 8B blocks at
// slot = eblock ^ (row&15) (16 slots x 32 rows -> 2 lanes/slot = conflict-
// free per m136); k_attn reads fragments as TWO ds_read_b64 instead of one
// ds_read_b128 (same LDS-pipe bytes, kills the 4-way conflict that cost
// 2.1M cycles). gload_lds staging stays byte-linear (swizzle is baked into
// the global panel layout by the prepass; read applies the same involution).
//
// MFMA 32x32x16: C col=lane&31, row=(reg&3)+8*(reg>>2)+4*(lane>>5);
// A row=lane&31, k=8*(lane>>5)+j. B col=lane&31, k=8*(lane>>5)+j.

typedef __attribute__((ext_vector_type(8))) __bf16 bf16x8;
typedef __attribute__((ext_vector_type(16))) float f32x16;
typedef __attribute__((ext_vector_type(4))) unsigned int u32x4;

#define TEMP2 (0.125f * 1.4426950408889634f)
#define LG2E 1.4426950408889634f

static __device__ __forceinline__ unsigned short f2bf(float x) {
  unsigned int u = __builtin_bit_cast(unsigned int, x);
  u += 0x7FFFu + ((u >> 16) & 1u);
  return (unsigned short)(u >> 16);
}
static __device__ __forceinline__ unsigned int cvtpk(float lo, float hi) {
  unsigned int r;
  asm("v_cvt_pk_bf16_f32 %0, %1, %2" : "=v"(r) : "v"(lo), "v"(hi));
  return r;
}
static __device__ __forceinline__ void gload16(const void* g, void* l) {
  __builtin_amdgcn_global_load_lds((const __attribute__((address_space(1))) void*)g,
                                   (__attribute__((address_space(3))) void*)l, 16, 0, 0);
}
// After: a = {a.lo32, b.lo32}, b = {a.hi32, b.hi32}
static __device__ __forceinline__ void plswap(unsigned int& a, unsigned int& b) {
  asm("v_permlane32_swap_b32 %0, %1" : "+v"(a), "+v"(b));
}
// two ds_read_b64 -> one bf16x8 fragment
static __device__ __forceinline__ bf16x8 ld2(const unsigned short* base,
                                             int o0, int o1) {
  uint2 lo = *(const uint2*)(base + o0);
  uint2 hi = *(const uint2*)(base + o1);
  u32x4 t;
  t[0] = lo.x; t[1] = lo.y; t[2] = hi.x; t[3] = hi.y;
  return __builtin_bit_cast(bf16x8, t);
}

// ---------------- balanced prepass: 512 blocks x 512 threads ----------------
__global__ __launch_bounds__(512) void k_prep2(
    const int* __restrict__ pos, unsigned int* __restrict__ pospk,
    const float* __restrict__ K, unsigned short* __restrict__ Kp,
    const float* __restrict__ V, unsigned short* __restrict__ Vt,
    const float* __restrict__ mask, const float* __restrict__ klm,
    int* __restrict__ flags) {
  __shared__ float ld[32][65];   // 8.3 KB transpose pool
  __shared__ int wf[8];
  int bid = blockIdx.x, tid = threadIdx.x;
  int gt = bid * 512 + tid;

  // ---- K relayout: 4 threads per (n,s,h) row; 8B-slot swizzle ----
  {
    int row = gt >> 2, q = gt & 3;
    int s = (row >> 4) & 1023;
    const float* src = K + row * 64 + q * 16;
    unsigned short rv[16];
#pragma unroll
    for (int j = 0; j < 4; ++j) {
      float4 v = *(const float4*)(src + j * 4);
      rv[j*4+0] = f2bf(v.x); rv[j*4+1] = f2bf(v.y);
      rv[j*4+2] = f2bf(v.z); rv[j*4+3] = f2bf(v.w);
    }
    int n = row >> 14, h = row & 15;
    unsigned short* dst = Kp + ((n * 16 + h) * 1024 + s) * 64;
#pragma unroll
    for (int c = 0; c < 4; ++c) {
      int eb = q * 4 + c;                 // e-block of 4 shorts (0..15)
      int sl = eb ^ (s & 15);
      *(uint2*)(dst + sl * 4) = *(const uint2*)(&rv[c * 4]);
    }
  }
  // ---- mask + klm nonzero scan ----
  float acc = 0.f;
  {
    float4 v = *(const float4*)(mask + gt * 4);
    acc += __builtin_fabsf(v.x) + __builtin_fabsf(v.y) +
           __builtin_fabsf(v.z) + __builtin_fabsf(v.w);
    if (gt < 1024) {
      float4 kv = *(const float4*)(klm + gt * 4);
      acc += __builtin_fabsf(kv.x) + __builtin_fabsf(kv.y) +
             __builtin_fabsf(kv.z) + __builtin_fabsf(kv.w);
    }
  }
  // ---- pos pack: one (n,l) row per wave, transposed out ----
  {
    int r = bid * 8 + (tid >> 6);        // [0,4096) = (n,l)
    int n = r >> 10, l = r & 1023;
    int lane = tid & 63;
    const int* prow = pos + r * 1024 + lane;
#pragma unroll
    for (int j = 0; j < 16; ++j) {
      unsigned long long m = __ballot(prow[j * 64] & 1);
      if (lane == 0) pospk[(n * 32 + 2 * j) * 1024 + l] = (unsigned int)m;
      else if (lane == 32) pospk[(n * 32 + 2 * j + 1) * 1024 + l] = (unsigned int)(m >> 32);
    }
  }
  // ---- V transpose: 2 tiles per block, half-tiles through LDS ----
#pragma unroll
  for (int tt = 0; tt < 2; ++tt) {
    int vt = bid * 2 + tt;               // [0,1024)
    int t16 = vt & 15, h = (vt >> 4) & 15, n = vt >> 8;
#pragma unroll
    for (int hf = 0; hf < 2; ++hf) {
      __syncthreads();
      {
        int sl = tid >> 4, dq = (tid & 15) * 4;
        int s_glob = t16 * 64 + hf * 32 + sl;
        float4 v = *(const float4*)(V + ((n * 1024 + s_glob) * 16 + h) * 64 + dq);
        ld[sl][dq + 0] = v.x; ld[sl][dq + 1] = v.y;
        ld[sl][dq + 2] = v.z; ld[sl][dq + 3] = v.w;
      }
      __syncthreads();
      if (tid < 256) {
        int d = tid >> 2, bq = (tid & 3) + hf * 4;   // 16B block (8 s-values)
        int sl0 = (tid & 3) * 8;
        unsigned short vals[8];
#pragma unroll
        for (int k = 0; k < 8; ++k) vals[k] = f2bf(ld[sl0 + k][d]);
        unsigned short* dst = Vt + ((n * 16 + h) * 64 + d) * 1024 + t16 * 64;
        int sb0 = bq * 2, sb1 = bq * 2 + 1;          // 8B s-blocks (0..15)
        *(uint2*)(dst + (sb0 ^ (d & 15)) * 4) = *(const uint2*)(&vals[0]);
        *(uint2*)(dst + (sb1 ^ (d & 15)) * 4) = *(const uint2*)(&vals[4]);
      }
    }
  }
  // ---- per-block flag (plain store, no init needed) ----
  __syncthreads();
  {
    unsigned long long bal = __ballot(acc != 0.f);
    if ((tid & 63) == 0) wf[tid >> 6] = (bal != 0ull) ? 1 : 0;
    __syncthreads();
    if (tid == 0 && flags) {
      int v = 0;
#pragma unroll
      for (int i = 0; i < 8; ++i) v |= wf[i];
      flags[bid] = v;
    }
  }
}

// ---------------- main flash-attention kernel ----------
// grid 512 = lblk*64 + n*16 + h ; 512 thr = 2 s-groups x 4 waves x 64.
__global__ __launch_bounds__(512) void k_attn(
    const float* __restrict__ Q, const float* __restrict__ mask,
    const float* __restrict__ klm, const float* __restrict__ ptab,
    const unsigned int* __restrict__ pospk,
    const unsigned short* __restrict__ Kp, const unsigned short* __restrict__ Vt,
    const int* __restrict__ flags,
    float* __restrict__ out) {
  __shared__ __align__(16) unsigned short KBA[2][4096];
  __shared__ __align__(16) unsigned short KBB[2][4096];
  __shared__ __align__(16) unsigned short VBA[2][4096];
  __shared__ __align__(16) unsigned short VBB[2][4096];
  __shared__ __align__(16) unsigned short VBC[2][4096];

  int bid = blockIdx.x;
  int tid = threadIdx.x;

  // ---- reduce the 512 per-block mask flags (blockDim == 512) ----
  int hcmg = 1;
  if (flags) {
    int v = flags[tid];
    unsigned long long bal = __ballot(v != 0);
    int* wf = (int*)KBB;
    if ((tid & 63) == 0) wf[tid >> 6] = (bal != 0ull) ? 1 : 0;
    __syncthreads();
    int r = 0;
#pragma unroll
    for (int i = 0; i < 8; ++i) r |= wf[i];
    hcmg = r;
    __syncthreads();
  }

  int nh = bid & 63;
  int n = nh >> 4, h = nh & 15, lblk = bid >> 6;
  int w8 = tid >> 6, lane = tid & 63;
  int g = w8 >> 2, w4 = w8 & 3;
  int l31 = lane & 31, h5 = lane >> 5;
  int l = lblk * 128 + w4 * 32 + l31;  // this lane's q-row (global)
  const int hcm = hcmg;

  // Q fragments (B of swapped QK^T), pre-scaled by temp2
  const float* qrow = Q + ((n * 1024 + l) * 16 + h) * 64;
  bf16x8 qf[4];
#pragma unroll
  for (int ke = 0; ke < 4; ++ke) {
    float4 a = *(const float4*)(qrow + ke * 16 + h5 * 8);
    float4 bq = *(const float4*)(qrow + ke * 16 + h5 * 8 + 4);
    u32x4 pk;
    pk[0] = cvtpk(a.x * TEMP2, a.y * TEMP2);
    pk[1] = cvtpk(a.z * TEMP2, a.w * TEMP2);
    pk[2] = cvtpk(bq.x * TEMP2, bq.y * TEMP2);
    pk[3] = cvtpk(bq.z * TEMP2, bq.w * TEMP2);
    qf[ke] = __builtin_bit_cast(bf16x8, pk);
  }
  const float delta2 = (ptab[16 + h] - ptab[h]) * LG2E;

  float mrun = -1e30f, lrun = 0.f;
  f32x16 Oc0 = {0,0,0,0,0,0,0,0,0,0,0,0,0,0,0,0};
  f32x16 Oc1 = {0,0,0,0,0,0,0,0,0,0,0,0,0,0,0,0};
  u32x4 pfA = {0,0,0,0}, pfB = {0,0,0,0}, pfC = {0,0,0,0}, pfD = {0,0,0,0};

  const unsigned short* KpB = Kp + nh * 65536;
  const unsigned short* VtB = Vt + nh * 65536;
  const float* mrowB = mask + l * 1024 + g * 512;
  const float* krowB = klm + n * 1024 + g * 512;
  const unsigned int* posB = pospk + (n * 32 + g * 16) * 1024 + l;
  const int h4 = h5 * 4;

  // loop-invariant 8B-slot read offsets (shorts): slot = eb ^ (l31&15)
  const int x15 = l31 & 15;
  const int h2 = h5 * 2;
  const int cA0 = ((0  + h2) ^ x15) * 4, cA1 = ((1  + h2) ^ x15) * 4;
  const int cB0 = ((4  + h2) ^ x15) * 4, cB1 = ((5  + h2) ^ x15) * 4;
  const int cC0 = ((8  + h2) ^ x15) * 4, cC1 = ((9  + h2) ^ x15) * 4;
  const int cD0 = ((12 + h2) ^ x15) * 4, cD1 = ((13 + h2) ^ x15) * 4;
  const int rb = l31 * 64;

  const unsigned short* kS = KpB + g * 32768 + w4 * 1024 + lane * 8;
  const unsigned short* vS = VtB + (w4 * 16 + (lane >> 3)) * 1024 + g * 512 + (lane & 7) * 8;
  const int kD = w4 * 1024 + lane * 8;

#define BF(x) __builtin_bit_cast(bf16x8, x)
#define MFMA(A, B, C) __builtin_amdgcn_mfma_f32_32x32x16_bf16(A, B, C, 0, 0, 0)
#define LDB2(ARR, RB, O0, O1) ld2(&ARR[g][(RB)], (O0), (O1))

  // ---- prologue: stage tile (g*8): K->KBA, V->VBA ----
#pragma unroll
  for (int j = 0; j < 2; ++j) {
    gload16(kS + j * 512, &KBA[g][kD + j * 512]);
    gload16(vS + j * 8192, &VBA[g][kD + j * 512]);
  }
  __syncthreads();

#define BODY(T, KR, KW, VR, VW, DO_PV, STG)                                    \
  {                                                                            \
    unsigned pwx = posB[((T) * 2) * 1024];                                     \
    unsigned pwy = posB[((T) * 2 + 1) * 1024];                                 \
    if (STG) {                                                                 \
      _Pragma("unroll")                                                        \
      for (int j = 0; j < 2; ++j) {                                            \
        gload16(kS + ((T) + 1) * 4096 + j * 512, &KW[g][kD + j * 512]);        \
        gload16(vS + ((T) + 1) * 64 + j * 8192, &VW[g][kD + j * 512]);         \
      }                                                                        \
    }                                                                          \
    f32x16 sv0 = {0,0,0,0,0,0,0,0,0,0,0,0,0,0,0,0};                            \
    f32x16 sv1 = {0,0,0,0,0,0,0,0,0,0,0,0,0,0,0,0};                            \
    __builtin_amdgcn_s_setprio(1);                                             \
    sv0 = MFMA(LDB2(KR, rb, cA0, cA1), qf[0], sv0);                            \
    sv1 = MFMA(LDB2(KR, rb + 2048, cA0, cA1), qf[0], sv1);                     \
    if (DO_PV) {                                                               \
      Oc0 = MFMA(LDB2(VR, rb, cA0, cA1), BF(pfA), Oc0);                        \
      Oc1 = MFMA(LDB2(VR, rb + 2048, cA0, cA1), BF(pfA), Oc1);                 \
    }                                                                          \
    sv0 = MFMA(LDB2(KR, rb, cB0, cB1), qf[1], sv0);                            \
    sv1 = MFMA(LDB2(KR, rb + 2048, cB0, cB1), qf[1], sv1);                     \
    if (DO_PV) {                                                               \
      Oc0 = MFMA(LDB2(VR, rb, cB0, cB1), BF(pfB), Oc0);                        \
      Oc1 = MFMA(LDB2(VR, rb + 2048, cB0, cB1), BF(pfB), Oc1);                 \
    }                                                                          \
    sv0 = MFMA(LDB2(KR, rb, cC0, cC1), qf[2], sv0);                            \
    sv1 = MFMA(LDB2(KR, rb + 2048, cC0, cC1), qf[2], sv1);                     \
    if (DO_PV) {                                                               \
      Oc0 = MFMA(LDB2(VR, rb, cC0, cC1), BF(pfC), Oc0);                        \
      Oc1 = MFMA(LDB2(VR, rb + 2048, cC0, cC1), BF(pfC), Oc1);                 \
    }                                                                          \
    sv0 = MFMA(LDB2(KR, rb, cD0, cD1), qf[3], sv0);                            \
    sv1 = MFMA(LDB2(KR, rb + 2048, cD0, cD1), qf[3], sv1);                     \
    if (DO_PV) {                                                               \
      Oc0 = MFMA(LDB2(VR, rb, cD0, cD1), BF(pfD), Oc0);                        \
      Oc1 = MFMA(LDB2(VR, rb + 2048, cD0, cD1), BF(pfD), Oc1);                 \
    }                                                                          \
    __builtin_amdgcn_s_setprio(0);                                             \
    if (hcm) {                                                                 \
      _Pragma("unroll")                                                        \
      for (int r2 = 0; r2 < 4; ++r2) {                                         \
        float4 mv0 = *(const float4*)(mrowB + (T) * 64 + r2 * 8 + h4);         \
        float4 kv0 = *(const float4*)(krowB + (T) * 64 + r2 * 8 + h4);         \
        float4 mv1 = *(const float4*)(mrowB + (T) * 64 + 32 + r2 * 8 + h4);    \
        float4 kv1 = *(const float4*)(krowB + (T) * 64 + 32 + r2 * 8 + h4);    \
        sv0[r2 * 4 + 0] += (mv0.x + kv0.x) * TEMP2;                            \
        sv0[r2 * 4 + 1] += (mv0.y + kv0.y) * TEMP2;                            \
        sv0[r2 * 4 + 2] += (mv0.z + kv0.z) * TEMP2;                            \
        sv0[r2 * 4 + 3] += (mv0.w + kv0.w) * TEMP2;                            \
        sv1[r2 * 4 + 0] += (mv1.x + kv1.x) * TEMP2;                            \
        sv1[r2 * 4 + 1] += (mv1.y + kv1.y) * TEMP2;                            \
        sv1[r2 * 4 + 2] += (mv1.z + kv1.z) * TEMP2;                            \
        sv1[r2 * 4 + 3] += (mv1.w + kv1.w) * TEMP2;                            \
      }                                                                        \
    }                                                                          \
    {                                                                          \
      unsigned pws0 = pwx >> h4;                                               \
      unsigned pws1 = pwy >> h4;                                               \
      _Pragma("unroll")                                                        \
      for (int r2 = 0; r2 < 4; ++r2)                                           \
        _Pragma("unroll")                                                      \
        for (int i = 0; i < 4; ++i) {                                          \
          float bit0 = (float)((pws0 >> (r2 * 8 + i)) & 1u);                   \
          float bit1 = (float)((pws1 >> (r2 * 8 + i)) & 1u);                   \
          sv0[r2 * 4 + i] = fmaf(bit0, delta2, sv0[r2 * 4 + i]);               \
          sv1[r2 * 4 + i] = fmaf(bit1, delta2, sv1[r2 * 4 + i]);               \
        }                                                                      \
    }                                                                          \
    {                                                                          \
      float m8[8];                                                             \
      _Pragma("unroll")                                                        \
      for (int i = 0; i < 8; ++i)                                              \
        m8[i] = fmaxf(fmaxf(sv0[2 * i], sv0[2 * i + 1]),                       \
                      fmaxf(sv1[2 * i], sv1[2 * i + 1]));                      \
      float m4a = fmaxf(m8[0], m8[1]), m4b = fmaxf(m8[2], m8[3]);              \
      float m4c = fmaxf(m8[4], m8[5]), m4d = fmaxf(m8[6], m8[7]);              \
      float tmax = fmaxf(fmaxf(m4a, m4b), fmaxf(m4c, m4d));                    \
      tmax = fmaxf(tmax, __shfl_xor(tmax, 32));                                \
      if (!__all(tmax <= mrun + 4.0f)) {                                       \
        float mnew = fmaxf(mrun, tmax);                                        \
        float sc = __builtin_amdgcn_exp2f(mrun - mnew);                        \
        lrun *= sc;                                                            \
        Oc0 *= sc; Oc1 *= sc;                                                  \
        mrun = mnew;                                                           \
      }                                                                        \
      float s8[8];                                                             \
      _Pragma("unroll")                                                        \
      for (int i = 0; i < 8; ++i) {                                            \
        float p0 = __builtin_amdgcn_exp2f(sv0[2 * i] - mrun);                  \
        float p1 = __builtin_amdgcn_exp2f(sv0[2 * i + 1] - mrun);              \
        float p2 = __builtin_amdgcn_exp2f(sv1[2 * i] - mrun);                  \
        float p3 = __builtin_amdgcn_exp2f(sv1[2 * i + 1] - mrun);              \
        sv0[2 * i] = p0; sv0[2 * i + 1] = p1;                                  \
        sv1[2 * i] = p2; sv1[2 * i + 1] = p3;                                  \
        s8[i] = (p0 + p1) + (p2 + p3);                                         \
      }                                                                        \
      float s4a = s8[0] + s8[1], s4b = s8[2] + s8[3];                          \
      float s4c = s8[4] + s8[5], s4d = s8[6] + s8[7];                          \
      lrun += (s4a + s4b) + (s4c + s4d);                                       \
    }                                                                          \
    {                                                                          \
      unsigned a0 = cvtpk(sv0[0], sv0[1]),   a1 = cvtpk(sv0[2], sv0[3]);       \
      unsigned a2 = cvtpk(sv0[4], sv0[5]),   a3 = cvtpk(sv0[6], sv0[7]);       \
      plswap(a0, a2); plswap(a1, a3);                                          \
      pfA[0] = a0; pfA[1] = a1; pfA[2] = a2; pfA[3] = a3;                      \
      unsigned b0_ = cvtpk(sv0[8], sv0[9]),   b1_ = cvtpk(sv0[10], sv0[11]);   \
      unsigned b2_ = cvtpk(sv0[12], sv0[13]), b3_ = cvtpk(sv0[14], sv0[15]);   \
      plswap(b0_, b2_); plswap(b1_, b3_);                                      \
      pfB[0] = b0_; pfB[1] = b1_; pfB[2] = b2_; pfB[3] = b3_;                  \
      unsigned c0 = cvtpk(sv1[0], sv1[1]),   c1 = cvtpk(sv1[2], sv1[3]);       \
      unsigned c2 = cvtpk(sv1[4], sv1[5]),   c3 = cvtpk(sv1[6], sv1[7]);       \
      plswap(c0, c2); plswap(c1, c3);                                          \
      pfC[0] = c0; pfC[1] = c1; pfC[2] = c2; pfC[3] = c3;                      \
      unsigned d0 = cvtpk(sv1[8], sv1[9]),   d1 = cvtpk(sv1[10], sv1[11]);     \
      unsigned d2 = cvtpk(sv1[12], sv1[13]), d3 = cvtpk(sv1[14], sv1[15]);     \
      plswap(d0, d2); plswap(d1, d3);                                          \
      pfD[0] = d0; pfD[1] = d1; pfD[2] = d2; pfD[3] = d3;                      \
    }                                                                          \
    if (STG) __syncthreads();                                                  \
  }

  // V(t) lives in buf t%3 (A,B,C); K(t) in buf t&1 (A,B).
  //     T   KR   KW   VR   VW  PV STG
  BODY( 0, KBA, KBB, VBA, VBB, 0, 1)
  BODY( 1, KBB, KBA, VBA, VBC, 1, 1)
  BODY( 2, KBA, KBB, VBB, VBA, 1, 1)
  BODY( 3, KBB, KBA, VBC, VBB, 1, 1)
  BODY( 4, KBA, KBB, VBA, VBC, 1, 1)
  BODY( 5, KBB, KBA, VBB, VBA, 1, 1)
  BODY( 6, KBA, KBB, VBC, VBB, 1, 1)
  BODY( 7, KBB, KBB, VBA, VBB, 1, 0)
#undef BODY

  // ---- epilogue PV(7): V(7) in VBB (staged body 6) ----
  __builtin_amdgcn_s_setprio(1);
  Oc0 = MFMA(LDB2(VBB, rb, cA0, cA1), BF(pfA), Oc0);
  Oc1 = MFMA(LDB2(VBB, rb + 2048, cA0, cA1), BF(pfA), Oc1);
  Oc0 = MFMA(LDB2(VBB, rb, cB0, cB1), BF(pfB), Oc0);
  Oc1 = MFMA(LDB2(VBB, rb + 2048, cB0, cB1), BF(pfB), Oc1);
  Oc0 = MFMA(LDB2(VBB, rb, cC0, cC1), BF(pfC), Oc0);
  Oc1 = MFMA(LDB2(VBB, rb + 2048, cC0, cC1), BF(pfC), Oc1);
  Oc0 = MFMA(LDB2(VBB, rb, cD0, cD1), BF(pfD), Oc0);
  Oc1 = MFMA(LDB2(VBB, rb + 2048, cD0, cD1), BF(pfD), Oc1);
  __builtin_amdgcn_s_setprio(0);
#undef MFMA
#undef BF
#undef LDB2

  // ---- merge the two s-half groups (exact), 2 rounds via VBA/VBB ----
  float lw = lrun + __shfl_xor(lrun, 32);
  __syncthreads();
#pragma unroll
  for (int r = 0; r < 2; ++r) {
    if (g == 1 && (w4 >> 1) == r) {
      float* row = ((w4 & 1) ? (float*)VBB : (float*)VBA) + lane * 36;
#pragma unroll
      for (int r2 = 0; r2 < 4; ++r2) {
        *(float4*)(row + r2 * 4) =
            make_float4(Oc0[4*r2+0], Oc0[4*r2+1], Oc0[4*r2+2], Oc0[4*r2+3]);
        *(float4*)(row + 16 + r2 * 4) =
            make_float4(Oc1[4*r2+0], Oc1[4*r2+1], Oc1[4*r2+2], Oc1[4*r2+3]);
      }
      row[32] = mrun;
      row[33] = lw;
    }
    __syncthreads();
    if (g == 0 && (w4 >> 1) == r) {
      const float* row = ((w4 & 1) ? (float*)VBB : (float*)VBA) + lane * 36;
      float m1 = row[32], l1 = row[33];
      float mm = fmaxf(mrun, m1);
      float s0e = __builtin_amdgcn_exp2f(mrun - mm);
      float s1e = __builtin_amdgcn_exp2f(m1 - mm);
      float ltot = lw * s0e + l1 * s1e;
      float inv = 1.0f / ltot;
      float* orow = out + ((n * 1024 + l) * 16 + h) * 64;
#pragma unroll
      for (int r2 = 0; r2 < 4; ++r2) {
        float4 o;
        o.x = (Oc0[4*r2+0] * s0e + row[r2*4+0] * s1e) * inv;
        o.y = (Oc0[4*r2+1] * s0e + row[r2*4+1] * s1e) * inv;
        o.z = (Oc0[4*r2+2] * s0e + row[r2*4+2] * s1e) * inv;
        o.w = (Oc0[4*r2+3] * s0e + row[r2*4+3] * s1e) * inv;
        *(float4*)(orow + r2 * 8 + h4) = o;
        o.x = (Oc1[4*r2+0] * s0e + row[16+r2*4+0] * s1e) * inv;
        o.y = (Oc1[4*r2+1] * s0e + row[16+r2*4+1] * s1e) * inv;
        o.z = (Oc1[4*r2+2] * s0e + row[16+r2*4+2] * s1e) * inv;
        o.w = (Oc1[4*r2+3] * s0e + row[16+r2*4+3] * s1e) * inv;
        *(float4*)(orow + 32 + r2 * 8 + h4) = o;
      }
    }
    __syncthreads();
  }
}

extern "C" void kernel_launch(void* const* d_in, const int* in_sizes, int n_in,
                              void* d_out, int out_size, void* d_ws, size_t ws_size,
                              hipStream_t stream) {
  const float* Q    = (const float*)d_in[0];
  const float* K    = (const float*)d_in[1];
  const float* V    = (const float*)d_in[2];
  const float* mask = (const float*)d_in[3];
  const float* klm  = (const float*)d_in[4];
  const float* ptab = (const float*)d_in[5];
  const int*   pos  = (const int*)d_in[6];
  float* out = (float*)d_out;

  char* ws = (char*)d_ws;
  // layout: pospk 512K | Kp 8M | Vt 8M | flags 2KB
  unsigned int*   pospk = (unsigned int*)ws;
  unsigned short* Kp    = (unsigned short*)(ws + (1 << 19));
  unsigned short* Vt    = (unsigned short*)(ws + (1 << 19) + (8 << 20));
  int*            flags = (int*)(ws + (1 << 19) + (16 << 20));
  const size_t need = (size_t)(1 << 19) + (size_t)(16 << 20) + 2048;
  if (ws_size < need) flags = nullptr;   // k_attn falls back to hcm=1

  k_prep2<<<512, 512, 0, stream>>>(pos, pospk, K, Kp, V, Vt, mask, klm, flags);
  k_attn<<<512, 512, 0, stream>>>(Q, mask, klm, ptab, pospk, Kp, Vt, flags, out);
}

// Round 17
// 55.493 us; speedup vs baseline: 1.0588x; 1.0588x over previous
//
#include <hip/hip_runtime.h>

// FullAttention_Spatial: N=4, L=S=1024, H=16, E=D=64, NUM_POS=2, fp32 in/out.
//
// score = temp*(QK + attn_mask[l,s] + klm[n,s]) + pos_table[pos[n,l,s]][h]
// pos in {0,1} => bias = T0[h] + bit*(T1[h]-T0[h]); T0 cancels in softmax.
// Log2-domain softmax; Q pre-scaled by temp2 = temp*log2e.
//
// R16 = REVERT to R14 (best verified: 55.8us total, k_attn 44.8us).
// R15's 8B-swizzle killed bank conflicts (2.11M -> 12K) but regressed time:
// doubled ds_read issue + de-coalesced prepass stores cost more than the
// conflicts did (LDS port was not the critical path). 16B blocks restored.
//
// Structure: balanced prepass k_prep2 (512x512, HBM-floor ~10us) + k_attn
// (8-wave blocks = 2 s-half groups x 4 waves, K dbuf x2 + V tbuf x3 = 80KB
// LDS, single barrier/body, stage-at-top, 32x32x16 swapped QK^T, P in
// registers via permlane32_swap, defer-max, mask-skip flag, transposed pospk).
// Occupancy: 2 blocks/CU (LDS) x 4 waves/SIMD (VGPR 124) - proven maximal.
//
// MFMA 32x32x16: C col=lane&31, row=(reg&3)+8*(reg>>2)+4*(lane>>5);
// A row=lane&31, k=8*(lane>>5)+j. B col=lane&31, k=8*(lane>>5)+j.

typedef __attribute__((ext_vector_type(8))) __bf16 bf16x8;
typedef __attribute__((ext_vector_type(16))) float f32x16;
typedef __attribute__((ext_vector_type(4))) unsigned int u32x4;

#define TEMP2 (0.125f * 1.4426950408889634f)
#define LG2E 1.4426950408889634f

static __device__ __forceinline__ unsigned short f2bf(float x) {
  unsigned int u = __builtin_bit_cast(unsigned int, x);
  u += 0x7FFFu + ((u >> 16) & 1u);
  return (unsigned short)(u >> 16);
}
static __device__ __forceinline__ unsigned int cvtpk(float lo, float hi) {
  unsigned int r;
  asm("v_cvt_pk_bf16_f32 %0, %1, %2" : "=v"(r) : "v"(lo), "v"(hi));
  return r;
}
static __device__ __forceinline__ void gload16(const void* g, void* l) {
  __builtin_amdgcn_global_load_lds((const __attribute__((address_space(1))) void*)g,
                                   (__attribute__((address_space(3))) void*)l, 16, 0, 0);
}
// After: a = {a.lo32, b.lo32}, b = {a.hi32, b.hi32}
static __device__ __forceinline__ void plswap(unsigned int& a, unsigned int& b) {
  asm("v_permlane32_swap_b32 %0, %1" : "+v"(a), "+v"(b));
}

// ---------------- balanced prepass: 512 blocks x 512 threads ----------------
__global__ __launch_bounds__(512) void k_prep2(
    const int* __restrict__ pos, unsigned int* __restrict__ pospk,
    const float* __restrict__ K, unsigned short* __restrict__ Kp,
    const float* __restrict__ V, unsigned short* __restrict__ Vt,
    const float* __restrict__ mask, const float* __restrict__ klm,
    int* __restrict__ flags) {
  __shared__ float ld[32][65];   // 8.3 KB transpose pool
  __shared__ int wf[8];
  int bid = blockIdx.x, tid = threadIdx.x;
  int gt = bid * 512 + tid;

  // ---- K relayout: 4 threads per (n,s,h) row ----
  {
    int row = gt >> 2, q = gt & 3;
    int s = (row >> 4) & 1023;
    const float* src = K + row * 64 + q * 16;
    unsigned short rv[16];
#pragma unroll
    for (int j = 0; j < 4; ++j) {
      float4 v = *(const float4*)(src + j * 4);
      rv[j*4+0] = f2bf(v.x); rv[j*4+1] = f2bf(v.y);
      rv[j*4+2] = f2bf(v.z); rv[j*4+3] = f2bf(v.w);
    }
    int n = row >> 14, h = row & 15;
    unsigned short* dst = Kp + ((n * 16 + h) * 1024 + s) * 64;
#pragma unroll
    for (int c = 0; c < 2; ++c) {
      int bb = q * 2 + c;
      int pb = bb ^ (s & 7);
      *(u32x4*)(dst + pb * 8) = *(const u32x4*)(&rv[c * 8]);
    }
  }
  // ---- mask + klm nonzero scan ----
  float acc = 0.f;
  {
    float4 v = *(const float4*)(mask + gt * 4);
    acc += __builtin_fabsf(v.x) + __builtin_fabsf(v.y) +
           __builtin_fabsf(v.z) + __builtin_fabsf(v.w);
    if (gt < 1024) {
      float4 kv = *(const float4*)(klm + gt * 4);
      acc += __builtin_fabsf(kv.x) + __builtin_fabsf(kv.y) +
             __builtin_fabsf(kv.z) + __builtin_fabsf(kv.w);
    }
  }
  // ---- pos pack: one (n,l) row per wave, transposed out ----
  {
    int r = bid * 8 + (tid >> 6);        // [0,4096) = (n,l)
    int n = r >> 10, l = r & 1023;
    int lane = tid & 63;
    const int* prow = pos + r * 1024 + lane;
#pragma unroll
    for (int j = 0; j < 16; ++j) {
      unsigned long long m = __ballot(prow[j * 64] & 1);
      if (lane == 0) pospk[(n * 32 + 2 * j) * 1024 + l] = (unsigned int)m;
      else if (lane == 32) pospk[(n * 32 + 2 * j + 1) * 1024 + l] = (unsigned int)(m >> 32);
    }
  }
  // ---- V transpose: 2 tiles per block, half-tiles through LDS ----
#pragma unroll
  for (int tt = 0; tt < 2; ++tt) {
    int vt = bid * 2 + tt;               // [0,1024)
    int t16 = vt & 15, h = (vt >> 4) & 15, n = vt >> 8;
#pragma unroll
    for (int hf = 0; hf < 2; ++hf) {
      __syncthreads();
      {
        int sl = tid >> 4, dq = (tid & 15) * 4;
        int s_glob = t16 * 64 + hf * 32 + sl;
        float4 v = *(const float4*)(V + ((n * 1024 + s_glob) * 16 + h) * 64 + dq);
        ld[sl][dq + 0] = v.x; ld[sl][dq + 1] = v.y;
        ld[sl][dq + 2] = v.z; ld[sl][dq + 3] = v.w;
      }
      __syncthreads();
      if (tid < 256) {
        int d = tid >> 2, bq = (tid & 3) + hf * 4;
        int sl0 = (tid & 3) * 8;
        unsigned short vals[8];
#pragma unroll
        for (int k = 0; k < 8; ++k) vals[k] = f2bf(ld[sl0 + k][d]);
        int pb = bq ^ (d & 7);
        unsigned short* dst = Vt + ((n * 16 + h) * 64 + d) * 1024 + t16 * 64;
        *(u32x4*)(dst + pb * 8) = *(const u32x4*)(&vals[0]);
      }
    }
  }
  // ---- per-block flag (plain store, no init needed) ----
  __syncthreads();
  {
    unsigned long long bal = __ballot(acc != 0.f);
    if ((tid & 63) == 0) wf[tid >> 6] = (bal != 0ull) ? 1 : 0;
    __syncthreads();
    if (tid == 0 && flags) {
      int v = 0;
#pragma unroll
      for (int i = 0; i < 8; ++i) v |= wf[i];
      flags[bid] = v;
    }
  }
}

// ---------------- main flash-attention kernel (R12 + flag reduce) ----------
// grid 512 = lblk*64 + n*16 + h ; 512 thr = 2 s-groups x 4 waves x 64.
__global__ __launch_bounds__(512) void k_attn(
    const float* __restrict__ Q, const float* __restrict__ mask,
    const float* __restrict__ klm, const float* __restrict__ ptab,
    const unsigned int* __restrict__ pospk,
    const unsigned short* __restrict__ Kp, const unsigned short* __restrict__ Vt,
    const int* __restrict__ flags,
    float* __restrict__ out) {
  __shared__ __align__(16) unsigned short KBA[2][4096];
  __shared__ __align__(16) unsigned short KBB[2][4096];
  __shared__ __align__(16) unsigned short VBA[2][4096];
  __shared__ __align__(16) unsigned short VBB[2][4096];
  __shared__ __align__(16) unsigned short VBC[2][4096];

  int bid = blockIdx.x;
  int tid = threadIdx.x;

  // ---- reduce the 512 per-block mask flags (blockDim == 512) ----
  int hcmg = 1;
  if (flags) {
    int v = flags[tid];
    unsigned long long bal = __ballot(v != 0);
    int* wf = (int*)KBB;
    if ((tid & 63) == 0) wf[tid >> 6] = (bal != 0ull) ? 1 : 0;
    __syncthreads();
    int r = 0;
#pragma unroll
    for (int i = 0; i < 8; ++i) r |= wf[i];
    hcmg = r;
    __syncthreads();
  }

  int nh = bid & 63;
  int n = nh >> 4, h = nh & 15, lblk = bid >> 6;
  int w8 = tid >> 6, lane = tid & 63;
  int g = w8 >> 2, w4 = w8 & 3;
  int l31 = lane & 31, h5 = lane >> 5;
  int l = lblk * 128 + w4 * 32 + l31;  // this lane's q-row (global)
  const int hcm = hcmg;

  // Q fragments (B of swapped QK^T), pre-scaled by temp2
  const float* qrow = Q + ((n * 1024 + l) * 16 + h) * 64;
  bf16x8 qf[4];
#pragma unroll
  for (int ke = 0; ke < 4; ++ke) {
    float4 a = *(const float4*)(qrow + ke * 16 + h5 * 8);
    float4 bq = *(const float4*)(qrow + ke * 16 + h5 * 8 + 4);
    u32x4 pk;
    pk[0] = cvtpk(a.x * TEMP2, a.y * TEMP2);
    pk[1] = cvtpk(a.z * TEMP2, a.w * TEMP2);
    pk[2] = cvtpk(bq.x * TEMP2, bq.y * TEMP2);
    pk[3] = cvtpk(bq.z * TEMP2, bq.w * TEMP2);
    qf[ke] = __builtin_bit_cast(bf16x8, pk);
  }
  const float delta2 = (ptab[16 + h] - ptab[h]) * LG2E;

  float mrun = -1e30f, lrun = 0.f;
  f32x16 Oc0 = {0,0,0,0,0,0,0,0,0,0,0,0,0,0,0,0};
  f32x16 Oc1 = {0,0,0,0,0,0,0,0,0,0,0,0,0,0,0,0};
  u32x4 pfA = {0,0,0,0}, pfB = {0,0,0,0}, pfC = {0,0,0,0}, pfD = {0,0,0,0};

  const unsigned short* KpB = Kp + nh * 65536;
  const unsigned short* VtB = Vt + nh * 65536;
  const float* mrowB = mask + l * 1024 + g * 512;
  const float* krowB = klm + n * 1024 + g * 512;
  const unsigned int* posB = pospk + (n * 32 + g * 16) * 1024 + l;
  const int h4 = h5 * 4;

  const int x7 = l31 & 7;
  const int co0 = ((0 + h5) ^ x7) * 8;
  const int co1 = ((2 + h5) ^ x7) * 8;
  const int co2 = ((4 + h5) ^ x7) * 8;
  const int co3 = ((6 + h5) ^ x7) * 8;
  const int rb = l31 * 64;

  const unsigned short* kS = KpB + g * 32768 + w4 * 1024 + lane * 8;
  const unsigned short* vS = VtB + (w4 * 16 + (lane >> 3)) * 1024 + g * 512 + (lane & 7) * 8;
  const int kD = w4 * 1024 + lane * 8;

#define BF(x) __builtin_bit_cast(bf16x8, x)
#define MFMA(A, B, C) __builtin_amdgcn_mfma_f32_32x32x16_bf16(A, B, C, 0, 0, 0)
#define LDB(ARR, OFF) BF(*(const u32x4*)&ARR[g][(OFF)])

  // ---- prologue: stage tile (g*8): K->KBA, V->VBA ----
#pragma unroll
  for (int j = 0; j < 2; ++j) {
    gload16(kS + j * 512, &KBA[g][kD + j * 512]);
    gload16(vS + j * 8192, &VBA[g][kD + j * 512]);
  }
  __syncthreads();

#define BODY(T, KR, KW, VR, VW, DO_PV, STG)                                    \
  {                                                                            \
    unsigned pwx = posB[((T) * 2) * 1024];                                     \
    unsigned pwy = posB[((T) * 2 + 1) * 1024];                                 \
    if (STG) {                                                                 \
      _Pragma("unroll")                                                        \
      for (int j = 0; j < 2; ++j) {                                            \
        gload16(kS + ((T) + 1) * 4096 + j * 512, &KW[g][kD + j * 512]);        \
        gload16(vS + ((T) + 1) * 64 + j * 8192, &VW[g][kD + j * 512]);         \
      }                                                                        \
    }                                                                          \
    f32x16 sv0 = {0,0,0,0,0,0,0,0,0,0,0,0,0,0,0,0};                            \
    f32x16 sv1 = {0,0,0,0,0,0,0,0,0,0,0,0,0,0,0,0};                            \
    __builtin_amdgcn_s_setprio(1);                                             \
    sv0 = MFMA(LDB(KR, rb + co0), qf[0], sv0);                                 \
    sv1 = MFMA(LDB(KR, rb + 2048 + co0), qf[0], sv1);                          \
    if (DO_PV) {                                                               \
      Oc0 = MFMA(LDB(VR, rb + co0), BF(pfA), Oc0);                             \
      Oc1 = MFMA(LDB(VR, rb + 2048 + co0), BF(pfA), Oc1);                      \
    }                                                                          \
    sv0 = MFMA(LDB(KR, rb + co1), qf[1], sv0);                                 \
    sv1 = MFMA(LDB(KR, rb + 2048 + co1), qf[1], sv1);                          \
    if (DO_PV) {                                                               \
      Oc0 = MFMA(LDB(VR, rb + co1), BF(pfB), Oc0);                             \
      Oc1 = MFMA(LDB(VR, rb + 2048 + co1), BF(pfB), Oc1);                      \
    }                                                                          \
    sv0 = MFMA(LDB(KR, rb + co2), qf[2], sv0);                                 \
    sv1 = MFMA(LDB(KR, rb + 2048 + co2), qf[2], sv1);                          \
    if (DO_PV) {                                                               \
      Oc0 = MFMA(LDB(VR, rb + co2), BF(pfC), Oc0);                             \
      Oc1 = MFMA(LDB(VR, rb + 2048 + co2), BF(pfC), Oc1);                      \
    }                                                                          \
    sv0 = MFMA(LDB(KR, rb + co3), qf[3], sv0);                                 \
    sv1 = MFMA(LDB(KR, rb + 2048 + co3), qf[3], sv1);                          \
    if (DO_PV) {                                                               \
      Oc0 = MFMA(LDB(VR, rb + co3), BF(pfD), Oc0);                             \
      Oc1 = MFMA(LDB(VR, rb + 2048 + co3), BF(pfD), Oc1);                      \
    }                                                                          \
    __builtin_amdgcn_s_setprio(0);                                             \
    if (hcm) {                                                                 \
      _Pragma("unroll")                                                        \
      for (int r2 = 0; r2 < 4; ++r2) {                                         \
        float4 mv0 = *(const float4*)(mrowB + (T) * 64 + r2 * 8 + h4);         \
        float4 kv0 = *(const float4*)(krowB + (T) * 64 + r2 * 8 + h4);         \
        float4 mv1 = *(const float4*)(mrowB + (T) * 64 + 32 + r2 * 8 + h4);    \
        float4 kv1 = *(const float4*)(krowB + (T) * 64 + 32 + r2 * 8 + h4);    \
        sv0[r2 * 4 + 0] += (mv0.x + kv0.x) * TEMP2;                            \
        sv0[r2 * 4 + 1] += (mv0.y + kv0.y) * TEMP2;                            \
        sv0[r2 * 4 + 2] += (mv0.z + kv0.z) * TEMP2;                            \
        sv0[r2 * 4 + 3] += (mv0.w + kv0.w) * TEMP2;                            \
        sv1[r2 * 4 + 0] += (mv1.x + kv1.x) * TEMP2;                            \
        sv1[r2 * 4 + 1] += (mv1.y + kv1.y) * TEMP2;                            \
        sv1[r2 * 4 + 2] += (mv1.z + kv1.z) * TEMP2;                            \
        sv1[r2 * 4 + 3] += (mv1.w + kv1.w) * TEMP2;                            \
      }                                                                        \
    }                                                                          \
    {                                                                          \
      unsigned pws0 = pwx >> h4;                                               \
      unsigned pws1 = pwy >> h4;                                               \
      _Pragma("unroll")                                                        \
      for (int r2 = 0; r2 < 4; ++r2)                                           \
        _Pragma("unroll")                                                      \
        for (int i = 0; i < 4; ++i) {                                          \
          float bit0 = (float)((pws0 >> (r2 * 8 + i)) & 1u);                   \
          float bit1 = (float)((pws1 >> (r2 * 8 + i)) & 1u);                   \
          sv0[r2 * 4 + i] = fmaf(bit0, delta2, sv0[r2 * 4 + i]);               \
          sv1[r2 * 4 + i] = fmaf(bit1, delta2, sv1[r2 * 4 + i]);               \
        }                                                                      \
    }                                                                          \
    {                                                                          \
      float m8[8];                                                             \
      _Pragma("unroll")                                                        \
      for (int i = 0; i < 8; ++i)                                              \
        m8[i] = fmaxf(fmaxf(sv0[2 * i], sv0[2 * i + 1]),                       \
                      fmaxf(sv1[2 * i], sv1[2 * i + 1]));                      \
      float m4a = fmaxf(m8[0], m8[1]), m4b = fmaxf(m8[2], m8[3]);              \
      float m4c = fmaxf(m8[4], m8[5]), m4d = fmaxf(m8[6], m8[7]);              \
      float tmax = fmaxf(fmaxf(m4a, m4b), fmaxf(m4c, m4d));                    \
      tmax = fmaxf(tmax, __shfl_xor(tmax, 32));                                \
      if (!__all(tmax <= mrun + 4.0f)) {                                       \
        float mnew = fmaxf(mrun, tmax);                                        \
        float sc = __builtin_amdgcn_exp2f(mrun - mnew);                        \
        lrun *= sc;                                                            \
        Oc0 *= sc; Oc1 *= sc;                                                  \
        mrun = mnew;                                                           \
      }                                                                        \
      float s8[8];                                                             \
      _Pragma("unroll")                                                        \
      for (int i = 0; i < 8; ++i) {                                            \
        float p0 = __builtin_amdgcn_exp2f(sv0[2 * i] - mrun);                  \
        float p1 = __builtin_amdgcn_exp2f(sv0[2 * i + 1] - mrun);              \
        float p2 = __builtin_amdgcn_exp2f(sv1[2 * i] - mrun);                  \
        float p3 = __builtin_amdgcn_exp2f(sv1[2 * i + 1] - mrun);              \
        sv0[2 * i] = p0; sv0[2 * i + 1] = p1;                                  \
        sv1[2 * i] = p2; sv1[2 * i + 1] = p3;                                  \
        s8[i] = (p0 + p1) + (p2 + p3);                                         \
      }                                                                        \
      float s4a = s8[0] + s8[1], s4b = s8[2] + s8[3];                          \
      float s4c = s8[4] + s8[5], s4d = s8[6] + s8[7];                          \
      lrun += (s4a + s4b) + (s4c + s4d);                                       \
    }                                                                          \
    {                                                                          \
      unsigned a0 = cvtpk(sv0[0], sv0[1]),   a1 = cvtpk(sv0[2], sv0[3]);       \
      unsigned a2 = cvtpk(sv0[4], sv0[5]),   a3 = cvtpk(sv0[6], sv0[7]);       \
      plswap(a0, a2); plswap(a1, a3);                                          \
      pfA[0] = a0; pfA[1] = a1; pfA[2] = a2; pfA[3] = a3;                      \
      unsigned b0_ = cvtpk(sv0[8], sv0[9]),   b1_ = cvtpk(sv0[10], sv0[11]);   \
      unsigned b2_ = cvtpk(sv0[12], sv0[13]), b3_ = cvtpk(sv0[14], sv0[15]);   \
      plswap(b0_, b2_); plswap(b1_, b3_);                                      \
      pfB[0] = b0_; pfB[1] = b1_; pfB[2] = b2_; pfB[3] = b3_;                  \
      unsigned c0 = cvtpk(sv1[0], sv1[1]),   c1 = cvtpk(sv1[2], sv1[3]);       \
      unsigned c2 = cvtpk(sv1[4], sv1[5]),   c3 = cvtpk(sv1[6], sv1[7]);       \
      plswap(c0, c2); plswap(c1, c3);                                          \
      pfC[0] = c0; pfC[1] = c1; pfC[2] = c2; pfC[3] = c3;                      \
      unsigned d0 = cvtpk(sv1[8], sv1[9]),   d1 = cvtpk(sv1[10], sv1[11]);     \
      unsigned d2 = cvtpk(sv1[12], sv1[13]), d3 = cvtpk(sv1[14], sv1[15]);     \
      plswap(d0, d2); plswap(d1, d3);                                          \
      pfD[0] = d0; pfD[1] = d1; pfD[2] = d2; pfD[3] = d3;                      \
    }                                                                          \
    if (STG) __syncthreads();                                                  \
  }

  // V(t) lives in buf t%3 (A,B,C); K(t) in buf t&1 (A,B).
  //     T   KR   KW   VR   VW  PV STG
  BODY( 0, KBA, KBB, VBA, VBB, 0, 1)
  BODY( 1, KBB, KBA, VBA, VBC, 1, 1)
  BODY( 2, KBA, KBB, VBB, VBA, 1, 1)
  BODY( 3, KBB, KBA, VBC, VBB, 1, 1)
  BODY( 4, KBA, KBB, VBA, VBC, 1, 1)
  BODY( 5, KBB, KBA, VBB, VBA, 1, 1)
  BODY( 6, KBA, KBB, VBC, VBB, 1, 1)
  BODY( 7, KBB, KBB, VBA, VBB, 1, 0)
#undef BODY

  // ---- epilogue PV(7): V(7) in VBB (staged body 6) ----
  __builtin_amdgcn_s_setprio(1);
  Oc0 = MFMA(LDB(VBB, rb + co0), BF(pfA), Oc0);
  Oc1 = MFMA(LDB(VBB, rb + 2048 + co0), BF(pfA), Oc1);
  Oc0 = MFMA(LDB(VBB, rb + co1), BF(pfB), Oc0);
  Oc1 = MFMA(LDB(VBB, rb + 2048 + co1), BF(pfB), Oc1);
  Oc0 = MFMA(LDB(VBB, rb + co2), BF(pfC), Oc0);
  Oc1 = MFMA(LDB(VBB, rb + 2048 + co2), BF(pfC), Oc1);
  Oc0 = MFMA(LDB(VBB, rb + co3), BF(pfD), Oc0);
  Oc1 = MFMA(LDB(VBB, rb + 2048 + co3), BF(pfD), Oc1);
  __builtin_amdgcn_s_setprio(0);
#undef MFMA
#undef BF
#undef LDB

  // ---- merge the two s-half groups (exact), 2 rounds via VBA/VBB ----
  float lw = lrun + __shfl_xor(lrun, 32);
  __syncthreads();
#pragma unroll
  for (int r = 0; r < 2; ++r) {
    if (g == 1 && (w4 >> 1) == r) {
      float* row = ((w4 & 1) ? (float*)VBB : (float*)VBA) + lane * 36;
#pragma unroll
      for (int r2 = 0; r2 < 4; ++r2) {
        *(float4*)(row + r2 * 4) =
            make_float4(Oc0[4*r2+0], Oc0[4*r2+1], Oc0[4*r2+2], Oc0[4*r2+3]);
        *(float4*)(row + 16 + r2 * 4) =
            make_float4(Oc1[4*r2+0], Oc1[4*r2+1], Oc1[4*r2+2], Oc1[4*r2+3]);
      }
      row[32] = mrun;
      row[33] = lw;
    }
    __syncthreads();
    if (g == 0 && (w4 >> 1) == r) {
      const float* row = ((w4 & 1) ? (float*)VBB : (float*)VBA) + lane * 36;
      float m1 = row[32], l1 = row[33];
      float mm = fmaxf(mrun, m1);
      float s0e = __builtin_amdgcn_exp2f(mrun - mm);
      float s1e = __builtin_amdgcn_exp2f(m1 - mm);
      float ltot = lw * s0e + l1 * s1e;
      float inv = 1.0f / ltot;
      float* orow = out + ((n * 1024 + l) * 16 + h) * 64;
#pragma unroll
      for (int r2 = 0; r2 < 4; ++r2) {
        float4 o;
        o.x = (Oc0[4*r2+0] * s0e + row[r2*4+0] * s1e) * inv;
        o.y = (Oc0[4*r2+1] * s0e + row[r2*4+1] * s1e) * inv;
        o.z = (Oc0[4*r2+2] * s0e + row[r2*4+2] * s1e) * inv;
        o.w = (Oc0[4*r2+3] * s0e + row[r2*4+3] * s1e) * inv;
        *(float4*)(orow + r2 * 8 + h4) = o;
        o.x = (Oc1[4*r2+0] * s0e + row[16+r2*4+0] * s1e) * inv;
        o.y = (Oc1[4*r2+1] * s0e + row[16+r2*4+1] * s1e) * inv;
        o.z = (Oc1[4*r2+2] * s0e + row[16+r2*4+2] * s1e) * inv;
        o.w = (Oc1[4*r2+3] * s0e + row[16+r2*4+3] * s1e) * inv;
        *(float4*)(orow + 32 + r2 * 8 + h4) = o;
      }
    }
    __syncthreads();
  }
}

extern "C" void kernel_launch(void* const* d_in, const int* in_sizes, int n_in,
                              void* d_out, int out_size, void* d_ws, size_t ws_size,
                              hipStream_t stream) {
  const float* Q    = (const float*)d_in[0];
  const float* K    = (const float*)d_in[1];
  const float* V    = (const float*)d_in[2];
  const float* mask = (const float*)d_in[3];
  const float* klm  = (const float*)d_in[4];
  const float* ptab = (const float*)d_in[5];
  const int*   pos  = (const int*)d_in[6];
  float* out = (float*)d_out;

  char* ws = (char*)d_ws;
  // layout: pospk 512K | Kp 8M | Vt 8M | flags 2KB
  unsigned int*   pospk = (unsigned int*)ws;
  unsigned short* Kp    = (unsigned short*)(ws + (1 << 19));
  unsigned short* Vt    = (unsigned short*)(ws + (1 << 19) + (8 << 20));
  int*            flags = (int*)(ws + (1 << 19) + (16 << 20));
  const size_t need = (size_t)(1 << 19) + (size_t)(16 << 20) + 2048;
  if (ws_size < need) flags = nullptr;   // k_attn falls back to hcm=1

  k_prep2<<<512, 512, 0, stream>>>(pos, pospk, K, Kp, V, Vt, mask, klm, flags);
  k_attn<<<512, 512, 0, stream>>>(Q, mask, klm, ptab, pospk, Kp, Vt, flags, out);
}